// Round 5
// baseline (158.761 us; speedup 1.0000x reference)
//
#include <hip/hip_runtime.h>
#include <stdint.h>

// Problem: B=16, C=64, H=W=128. fp32 in/out.
#define NB   16
#define NCH  64
#define HH   128
#define NPOS (HH*HH)        // 16384 spatial positions

typedef short bf16x8 __attribute__((ext_vector_type(8)));   // 8 bf16 = 4 VGPRs
typedef float f32x4  __attribute__((ext_vector_type(4)));

__device__ __forceinline__ unsigned short f2bf(float f){
  unsigned int u = __float_as_uint(f);
  u += 0x7FFFu + ((u>>16)&1u);          // RNE; inputs finite
  return (unsigned short)(u>>16);
}
__device__ __forceinline__ unsigned int pk2(float a, float b){
  return (unsigned int)f2bf(a) | ((unsigned int)f2bf(b)<<16);
}
__device__ __forceinline__ bf16x8 pk8(float4 a, float4 b){
  union { bf16x8 v; unsigned int u[4]; } r;
  r.u[0] = pk2(a.x, a.y); r.u[1] = pk2(a.z, a.w);
  r.u[2] = pk2(b.x, b.y); r.u[3] = pk2(b.z, b.w);
  return r.v;
}

// XOR swizzle on byte bits 4-6: spreads 16 consecutive rows over 8 16B slots
// (2 rows/slot = 2-way = free on b128 frag reads, m136).
__device__ __forceinline__ int swz(int row, int cb){
  return cb ^ (((row & 7) ^ ((row >> 3) & 7)) << 4);
}

__device__ __forceinline__ uint4 shfl_xor16(uint4 v){
  uint4 r;
  r.x = (unsigned int)__shfl_xor((int)v.x, 16);
  r.y = (unsigned int)__shfl_xor((int)v.y, 16);
  r.z = (unsigned int)__shfl_xor((int)v.z, 16);
  r.w = (unsigned int)__shfl_xor((int)v.w, 16);
  return r;
}
__device__ __forceinline__ unsigned short elem16(uint4 v, int u){
  unsigned int d = (&v.x)[u>>1];
  return (unsigned short)((u&1) ? (d>>16) : (d&0xffffu));
}

// Paired transposed write: even lanes (l>>4 even) write uint covering rows
// (row,row+1) of T-column; 2 writers per 8B region on distinct dwords = free.
#define TWRITE(BUF, MINE, PART, rowv, colv)                          \
  { _Pragma("unroll")                                                \
    for (int u=0; u<8; ++u){                                         \
      int tr = (colv) + u;                                           \
      unsigned int pkv = (unsigned int)elem16((MINE),u) |            \
                         ((unsigned int)elem16((PART),u)<<16);       \
      *(unsigned int*)((BUF) + tr*256 + swz(tr, (rowv)*2)) = pkv;    \
    } }

// ---------------- Kernel 1: Q/V (m=0, from x) and K (m=1, from att) -------
// MFMA conv1x1+ReLU -> bf16. 256 thr, 128-position tile.
// LDS = Xs only (16KB): W/bias fragments loaded directly from global (L2-hot)
// -> 6-8 blocks/CU. Output via LDS bounce (reuses Xs) -> coalesced uint4.
__global__ __launch_bounds__(256, 6) void rc_conv_in(
    const float* __restrict__ x, const float* __restrict__ att,
    const float* __restrict__ w0, const float* __restrict__ b0,
    const float* __restrict__ w1, const float* __restrict__ b1,
    const float* __restrict__ w2, const float* __restrict__ b2,
    unsigned short* __restrict__ Qb, unsigned short* __restrict__ Kb,
    unsigned short* __restrict__ Vb)
{
  __shared__ char Xs[16384];           // 128 p-rows x 128 B; bounce: 64 x 256 B

  const int tid = threadIdx.x;
  const int m  = blockIdx.z;
  const int b  = blockIdx.y;
  const int pblock = blockIdx.x * 128;
  const float* src = m ? att : x;
  const int w = tid>>6, l = tid&63, lq = l>>4, lm = l&15;
  const int orow = 16*w + lm;

  // ---- W fragments direct from global (L2-cached across blocks) ----
  const float* wAp = (m ? w1 : w0) + orow*64;
  bf16x8 aQ[2], aV[2] = {};
  {
    float4 a0 = *(const float4*)(wAp + lq*8);
    float4 a1 = *(const float4*)(wAp + lq*8 + 4);
    float4 a2 = *(const float4*)(wAp + 32 + lq*8);
    float4 a3 = *(const float4*)(wAp + 32 + lq*8 + 4);
    aQ[0] = pk8(a0, a1); aQ[1] = pk8(a2, a3);
    if (m == 0){
      const float* wBp = w2 + orow*64;
      float4 g0 = *(const float4*)(wBp + lq*8);
      float4 g1 = *(const float4*)(wBp + lq*8 + 4);
      float4 g2 = *(const float4*)(wBp + 32 + lq*8);
      float4 g3 = *(const float4*)(wBp + 32 + lq*8 + 4);
      aV[0] = pk8(g0, g1); aV[1] = pk8(g2, g3);
    }
  }
  float4 bQ4 = *(const float4*)((m ? b1 : b0) + 16*w + 4*lq);
  float4 bV4 = (m==0) ? *(const float4*)(b2 + 16*w + 4*lq) : (float4){0,0,0,0};

  // ---- stage X tile: all 8 loads in flight, then transpose-pack to LDS ----
  const float* S = src + (size_t)b*NCH*NPOS + pblock;
  float4 xr[2][4];
  #pragma unroll
  for (int g=0; g<2; ++g){
    int unit = tid + 256*g;           // 0..511 = 16 cquads x 32 pgroups
    int q  = unit >> 5;               // channel quad 0..15
    int p4 = (unit & 31) << 2;        // position 0..127 step 4
    #pragma unroll
    for (int j=0;j<4;j++)
      xr[g][j] = *(const float4*)(S + (size_t)(4*q+j)*NPOS + p4);
  }
  #pragma unroll
  for (int g=0; g<2; ++g){
    int unit = tid + 256*g;
    int q  = unit >> 5;
    int p4 = (unit & 31) << 2;
    const float* c0 = (const float*)&xr[g][0];
    const float* c1 = (const float*)&xr[g][1];
    const float* c2 = (const float*)&xr[g][2];
    const float* c3 = (const float*)&xr[g][3];
    #pragma unroll
    for (int u=0; u<4; ++u){
      uint2 pk;
      pk.x = pk2(c0[u], c1[u]);
      pk.y = pk2(c2[u], c3[u]);
      *(uint2*)(Xs + (p4+u)*128 + swz(p4+u, q*8)) = pk;
    }
  }
  __syncthreads();

  // ---- MFMA: D[o',p'] = sum_c W[o,c]*X[p,c] ----
  f32x4 accQ[8], accV[8];
  #pragma unroll
  for (int pt=0;pt<8;pt++){ accQ[pt]=(f32x4){0,0,0,0}; accV[pt]=(f32x4){0,0,0,0}; }
  #pragma unroll
  for (int pt=0; pt<8; ++pt){
    int prow = pt*16 + lm;
    bf16x8 bx0 = *(const bf16x8*)(Xs + prow*128 + swz(prow,      lq*16));
    bf16x8 bx1 = *(const bf16x8*)(Xs + prow*128 + swz(prow, 64 + lq*16));
    accQ[pt] = __builtin_amdgcn_mfma_f32_16x16x32_bf16(aQ[0], bx0, accQ[pt], 0,0,0);
    accQ[pt] = __builtin_amdgcn_mfma_f32_16x16x32_bf16(aQ[1], bx1, accQ[pt], 0,0,0);
    if (m == 0){
      accV[pt] = __builtin_amdgcn_mfma_f32_16x16x32_bf16(aV[0], bx0, accV[pt], 0,0,0);
      accV[pt] = __builtin_amdgcn_mfma_f32_16x16x32_bf16(aV[1], bx1, accV[pt], 0,0,0);
    }
  }

  // ---- bounce + coalesced store (Xs reused as 64 o-rows x 256 B) ----
  unsigned short* dA = (m ? Kb : Qb) + (size_t)b*NCH*NPOS;
  unsigned short* dB = Vb + (size_t)b*NCH*NPOS;
  const float* bQv = (const float*)&bQ4;
  const float* bVv = (const float*)&bV4;
  const int skw = 32*((4*w + lq) & 7);     // = 32*((o>>2)&7) for this quarter

  __syncthreads();                          // all MFMA frag reads of Xs done
  #pragma unroll
  for (int pt=0; pt<8; ++pt){
    #pragma unroll
    for (int r4=0;r4<4;r4++){
      int o = 16*w + 4*lq + r4;
      int p = pt*16 + lm;
      *(unsigned short*)(Xs + o*256 + ((2*p + skw) & 255)) =
          f2bf(fmaxf(accQ[pt][r4] + bQv[r4], 0.f));
    }
  }
  __syncthreads();
  {
    int o = tid >> 2, jj = tid & 3;
    int sk2 = 32*((o>>2)&7);
    #pragma unroll
    for (int i=0;i<4;i++){
      int j = i*4 + jj;                    // 16B chunk index in row
      uint4 v = *(const uint4*)(Xs + o*256 + ((j*16 + sk2) & 255));
      *(uint4*)(dA + (size_t)o*NPOS + pblock + j*8) = v;
    }
  }
  if (m == 0){
    __syncthreads();                        // store-reads done before overwrite
    #pragma unroll
    for (int pt=0; pt<8; ++pt){
      #pragma unroll
      for (int r4=0;r4<4;r4++){
        int o = 16*w + 4*lq + r4;
        int p = pt*16 + lm;
        *(unsigned short*)(Xs + o*256 + ((2*p + skw) & 255)) =
            f2bf(fmaxf(accV[pt][r4] + bVv[r4], 0.f));
      }
    }
    __syncthreads();
    int o = tid >> 2, jj = tid & 3;
    int sk2 = 32*((o>>2)&7);
    #pragma unroll
    for (int i=0;i<4;i++){
      int j = i*4 + jj;
      uint4 v = *(const uint4*)(Xs + o*256 + ((j*16 + sk2) & 255));
      *(uint4*)(dB + (size_t)o*NPOS + pblock + j*8) = v;
    }
  }
}

// ---------------- Kernel 2: fused per-(b,c) MFMA attention ----------------
// 512 blocks x 512 threads (8 waves), 2 (b,c) problems per block pipelined:
// problem p+1's global loads are issued during problem p's compute phases.
// LDS = 4 x 32KB swizzled buffers. Paired-lane transposed staging.
__global__ __launch_bounds__(512, 2) void rc_attention_mfma(
    const unsigned short* __restrict__ Qb, const unsigned short* __restrict__ Kb,
    const unsigned short* __restrict__ Vb, unsigned short* __restrict__ Pb)
{
  extern __shared__ char lds[];
  char* B0 = lds;
  char* B1 = lds + 32768;
  char* B2 = lds + 65536;
  char* B3 = lds + 98304;
  const int tid = threadIdx.x;
  const int l  = tid & 63;
  const int w  = tid >> 6;          // wave 0..7
  const int lq = l >> 4;            // quarter 0..3
  const int lm = l & 15;
  const bool evenh = ((l >> 4) & 1) == 0;
  const size_t gb0 = (size_t)(blockIdx.x * 2) * NPOS;

  // ---- problem-0 loads (12 uint4 in flight) ----
  uint4 qr[4], kr[4], vr[4], qrn[4], krn[4], vrn[4];
  #pragma unroll
  for (int i=0;i<4;i++){
    size_t e = (size_t)(tid + 512*i)*8;
    qr[i] = *(const uint4*)(Qb + gb0 + e);
    kr[i] = *(const uint4*)(Kb + gb0 + e);
    vr[i] = *(const uint4*)(Vb + gb0 + e);
  }

  #pragma unroll
  for (int p=0; p<2; ++p){
    const size_t gb = gb0 + (size_t)p*NPOS;

    // ---- stage Q,K rm (B0,B1) + transposed (B2,B3, paired writes) ----
    #pragma unroll
    for (int i=0;i<4;i++){
      int e = (tid + 512*i)*8;
      int row = e >> 7, col = e & 127;
      uint4 q = qr[i], k = kr[i];
      *(uint4*)(B0 + row*256 + swz(row, col*2)) = q;
      *(uint4*)(B1 + row*256 + swz(row, col*2)) = k;
      uint4 qp = shfl_xor16(q), kp = shfl_xor16(k);
      if (evenh){
        TWRITE(B2, q, qp, row, col);
        TWRITE(B3, k, kp, row, col);
      }
    }
    if (p == 0){                       // prefetch next problem's Q,K
      #pragma unroll
      for (int i=0;i<4;i++){
        size_t e = (size_t)(tid + 512*i)*8;
        qrn[i] = *(const uint4*)(Qb + gb0 + NPOS + e);
        krn[i] = *(const uint4*)(Kb + gb0 + NPOS + e);
      }
    }
    __syncthreads();

    // ---- P1: S1T = K * Q^T ----
    f32x4 acc1[8];
    #pragma unroll
    for (int t=0;t<8;t++) acc1[t] = (f32x4){0.f,0.f,0.f,0.f};
    {
      bf16x8 bq[4];
      #pragma unroll
      for (int kk=0;kk<4;kk++){
        int r = 16*w + lm;
        bq[kk] = *(const bf16x8*)(B0 + r*256 + swz(r, kk*64 + lq*16));
      }
      #pragma unroll
      for (int kk=0;kk<4;kk++){
        #pragma unroll
        for (int jt=0;jt<8;jt++){
          int jr = jt*16 + lm;
          bf16x8 ak = *(const bf16x8*)(B1 + jr*256 + swz(jr, kk*64 + lq*16));
          acc1[jt] = __builtin_amdgcn_mfma_f32_16x16x32_bf16(ak, bq[kk], acc1[jt], 0,0,0);
        }
      }
    }
    unsigned int a1p[8][2];
    {
      float mx = -1e30f;
      #pragma unroll
      for (int t=0;t<8;t++)
        mx = fmaxf(mx, fmaxf(fmaxf(acc1[t][0], acc1[t][1]), fmaxf(acc1[t][2], acc1[t][3])));
      mx = fmaxf(mx, __shfl_xor(mx, 16));
      mx = fmaxf(mx, __shfl_xor(mx, 32));
      float sum = 0.f;
      #pragma unroll
      for (int t=0;t<8;t++){
        #pragma unroll
        for (int r4=0;r4<4;r4++){ float e = __expf(acc1[t][r4] - mx); acc1[t][r4] = e; sum += e; }
      }
      sum += __shfl_xor(sum, 16);
      sum += __shfl_xor(sum, 32);
      float inv = 1.f/sum;
      #pragma unroll
      for (int t=0;t<8;t++){
        a1p[t][0] = pk2(acc1[t][0]*inv, acc1[t][1]*inv);
        a1p[t][1] = pk2(acc1[t][2]*inv, acc1[t][3]*inv);
      }
    }

    // ---- P2: S2 = K^T * Q ----
    f32x4 acc2[8];
    #pragma unroll
    for (int t=0;t<8;t++) acc2[t] = (f32x4){0.f,0.f,0.f,0.f};
    {
      bf16x8 akt[4];
      #pragma unroll
      for (int kk=0;kk<4;kk++){
        int ir = 16*w + lm;
        akt[kk] = *(const bf16x8*)(B3 + ir*256 + swz(ir, kk*64 + lq*16));
      }
      #pragma unroll
      for (int kk=0;kk<4;kk++){
        #pragma unroll
        for (int ct=0;ct<8;ct++){
          int jr = ct*16 + lm;
          bf16x8 bqt = *(const bf16x8*)(B2 + jr*256 + swz(jr, kk*64 + lq*16));
          acc2[ct] = __builtin_amdgcn_mfma_f32_16x16x32_bf16(akt[kk], bqt, acc2[ct], 0,0,0);
        }
      }
    }
    unsigned int a2p[8][2];
    {
      float m0=-1e30f, m1=-1e30f, m2=-1e30f, m3=-1e30f;
      #pragma unroll
      for (int t=0;t<8;t++){
        m0 = fmaxf(m0, acc2[t][0]); m1 = fmaxf(m1, acc2[t][1]);
        m2 = fmaxf(m2, acc2[t][2]); m3 = fmaxf(m3, acc2[t][3]);
      }
      #pragma unroll
      for (int d=1; d<16; d<<=1){
        m0 = fmaxf(m0, __shfl_xor(m0,d)); m1 = fmaxf(m1, __shfl_xor(m1,d));
        m2 = fmaxf(m2, __shfl_xor(m2,d)); m3 = fmaxf(m3, __shfl_xor(m3,d));
      }
      float s0=0.f, s1=0.f, s2=0.f, s3=0.f;
      #pragma unroll
      for (int t=0;t<8;t++){
        float e0 = __expf(acc2[t][0]-m0); acc2[t][0]=e0; s0 += e0;
        float e1 = __expf(acc2[t][1]-m1); acc2[t][1]=e1; s1 += e1;
        float e2 = __expf(acc2[t][2]-m2); acc2[t][2]=e2; s2 += e2;
        float e3 = __expf(acc2[t][3]-m3); acc2[t][3]=e3; s3 += e3;
      }
      #pragma unroll
      for (int d=1; d<16; d<<=1){
        s0 += __shfl_xor(s0,d); s1 += __shfl_xor(s1,d);
        s2 += __shfl_xor(s2,d); s3 += __shfl_xor(s3,d);
      }
      float i0=1.f/s0, i1=1.f/s1, i2=1.f/s2, i3=1.f/s3;
      #pragma unroll
      for (int t=0;t<8;t++){
        a2p[t][0] = pk2(acc2[t][0]*i0, acc2[t][1]*i1);
        a2p[t][1] = pk2(acc2[t][2]*i2, acc2[t][3]*i3);
      }
    }

    __syncthreads();   // all P1/P2 LDS reads complete -> buffers reusable

    // ---- write A1 -> B3 (rm), A2T -> B2 (rm), VT -> B1 (paired) ----
    {
      int r = 16*w + lm;
      #pragma unroll
      for (int t=0;t<8;t++)
        *(uint2*)(B3 + r*256 + swz(r, t*32 + lq*8)) = make_uint2(a1p[t][0], a1p[t][1]);
    }
    #pragma unroll
    for (int t=0;t<8;t++){
      int jr = t*16 + lm;
      *(uint2*)(B2 + jr*256 + swz(jr, 32*w + lq*8)) = make_uint2(a2p[t][0], a2p[t][1]);
    }
    #pragma unroll
    for (int i=0;i<4;i++){
      int e = (tid + 512*i)*8;
      int row = e>>7, col = e&127;
      uint4 v = vr[i];
      uint4 vp = shfl_xor16(v);
      if (evenh) TWRITE(B1, v, vp, row, col);
    }
    if (p == 0){                       // prefetch next problem's V
      #pragma unroll
      for (int i=0;i<4;i++){
        size_t e = (size_t)(tid + 512*i)*8;
        vrn[i] = *(const uint4*)(Vb + gb0 + NPOS + e);
      }
    }
    __syncthreads();

    // ---- P3: MT = V^T * A1^T ----
    f32x4 acc3[8];
    #pragma unroll
    for (int t=0;t<8;t++) acc3[t] = (f32x4){0.f,0.f,0.f,0.f};
    {
      bf16x8 av[4];
      #pragma unroll
      for (int kk=0;kk<4;kk++){
        int jr = 16*w + lm;
        av[kk] = *(const bf16x8*)(B1 + jr*256 + swz(jr, kk*64 + lq*16));
      }
      #pragma unroll
      for (int kk=0;kk<4;kk++){
        #pragma unroll
        for (int rt=0;rt<8;rt++){
          int rr = rt*16 + lm;
          bf16x8 ba = *(const bf16x8*)(B3 + rr*256 + swz(rr, kk*64 + lq*16));
          acc3[rt] = __builtin_amdgcn_mfma_f32_16x16x32_bf16(av[kk], ba, acc3[rt], 0,0,0);
        }
      }
    }
    #pragma unroll
    for (int rt=0;rt<8;rt++){
      int rr = rt*16 + lm;
      unsigned int p0 = pk2(acc3[rt][0], acc3[rt][1]);
      unsigned int p1 = pk2(acc3[rt][2], acc3[rt][3]);
      *(uint2*)(B0 + rr*256 + swz(rr, 32*w + lq*8)) = make_uint2(p0, p1);
    }
    __syncthreads();

    // ---- P4: P = M * A2 -> global bf16 ----
    f32x4 acc4[8];
    #pragma unroll
    for (int t=0;t<8;t++) acc4[t] = (f32x4){0.f,0.f,0.f,0.f};
    {
      bf16x8 am[4];
      #pragma unroll
      for (int kk=0;kk<4;kk++){
        int rr = 16*w + lm;
        am[kk] = *(const bf16x8*)(B0 + rr*256 + swz(rr, kk*64 + lq*16));
      }
      #pragma unroll
      for (int kk=0;kk<4;kk++){
        #pragma unroll
        for (int ct=0;ct<8;ct++){
          int jr = ct*16 + lm;
          bf16x8 ba2 = *(const bf16x8*)(B2 + jr*256 + swz(jr, kk*64 + lq*16));
          acc4[ct] = __builtin_amdgcn_mfma_f32_16x16x32_bf16(am[kk], ba2, acc4[ct], 0,0,0);
        }
      }
    }
    unsigned short* pout = Pb + gb;
    #pragma unroll
    for (int ct=0;ct<8;ct++){
      #pragma unroll
      for (int r4=0;r4<4;r4++){
        int rr = 16*w + lq*4 + r4;
        pout[rr*HH + ct*16 + lm] = f2bf(acc4[ct][r4]);
      }
    }

    if (p == 0){
      __syncthreads();                 // all P4 reads done before restaging
      #pragma unroll
      for (int i=0;i<4;i++){ qr[i]=qrn[i]; kr[i]=krn[i]; vr[i]=vrn[i]; }
    }
  }
}

// ---------------- Kernel 3: out = relu(conv1x1(P, w3, b3)) fp32, MFMA -----
// LDS = Xs only (16KB): W3 frags direct from global -> 6-8 blocks/CU.
__global__ __launch_bounds__(256, 6) void rc_conv_out(
    const unsigned short* __restrict__ Pb, const float* __restrict__ w3,
    const float* __restrict__ b3, float* __restrict__ out)
{
  __shared__ char Xs[16384];           // 128 p-rows x 128 B

  const int tid = threadIdx.x;
  const int b  = blockIdx.y;
  const int pblock = blockIdx.x * 128;
  const int w = tid>>6, l = tid&63, lq = l>>4, lm = l&15;
  const int orow = 16*w + lm;

  bf16x8 aW[2];
  {
    const float* wp = w3 + orow*64;
    float4 a0 = *(const float4*)(wp + lq*8);
    float4 a1 = *(const float4*)(wp + lq*8 + 4);
    float4 a2 = *(const float4*)(wp + 32 + lq*8);
    float4 a3 = *(const float4*)(wp + 32 + lq*8 + 4);
    aW[0] = pk8(a0, a1); aW[1] = pk8(a2, a3);
  }
  float4 bv4 = *(const float4*)(b3 + 16*w + 4*lq);
  const float* bv = (const float*)&bv4;

  // ---- stage P tile: all 8 loads in flight, then pack to LDS ----
  const unsigned short* S = Pb + (size_t)b*NCH*NPOS + pblock;
  uint2 pr[2][4];
  #pragma unroll
  for (int g=0; g<2; ++g){
    int unit = tid + 256*g;
    int q  = unit >> 5;
    int p4 = (unit & 31) << 2;
    #pragma unroll
    for (int j=0;j<4;j++)
      pr[g][j] = *(const uint2*)(S + (size_t)(4*q+j)*NPOS + p4);
  }
  #pragma unroll
  for (int g=0; g<2; ++g){
    int unit = tid + 256*g;
    int q  = unit >> 5;
    int p4 = (unit & 31) << 2;
    const unsigned short* e0 = (const unsigned short*)&pr[g][0];
    const unsigned short* e1 = (const unsigned short*)&pr[g][1];
    const unsigned short* e2 = (const unsigned short*)&pr[g][2];
    const unsigned short* e3 = (const unsigned short*)&pr[g][3];
    #pragma unroll
    for (int u=0; u<4; ++u){
      uint2 pk;
      pk.x = (unsigned int)e0[u] | ((unsigned int)e1[u]<<16);
      pk.y = (unsigned int)e2[u] | ((unsigned int)e3[u]<<16);
      *(uint2*)(Xs + (p4+u)*128 + swz(p4+u, q*8)) = pk;
    }
  }
  __syncthreads();

  float* dst = out + (size_t)b*NCH*NPOS;
  #pragma unroll
  for (int pt=0; pt<8; ++pt){
    int prow = pt*16 + lm;
    bf16x8 bx0 = *(const bf16x8*)(Xs + prow*128 + swz(prow,      lq*16));
    bf16x8 bx1 = *(const bf16x8*)(Xs + prow*128 + swz(prow, 64 + lq*16));
    f32x4 acc = (f32x4){0.f,0.f,0.f,0.f};
    acc = __builtin_amdgcn_mfma_f32_16x16x32_bf16(aW[0], bx0, acc, 0,0,0);
    acc = __builtin_amdgcn_mfma_f32_16x16x32_bf16(aW[1], bx1, acc, 0,0,0);
    int p = pblock + pt*16 + lm;
    #pragma unroll
    for (int r4=0;r4<4;r4++){
      int o = 16*w + 4*lq + r4;
      dst[(size_t)o*NPOS + p] = fmaxf(acc[r4] + bv[r4], 0.f);
    }
  }
}

extern "C" void kernel_launch(void* const* d_in, const int* in_sizes, int n_in,
                              void* d_out, int out_size, void* d_ws, size_t ws_size,
                              hipStream_t stream)
{
  const float* x   = (const float*)d_in[0];
  const float* att = (const float*)d_in[1];
  const float* w0  = (const float*)d_in[2]; const float* b0 = (const float*)d_in[3];
  const float* w1  = (const float*)d_in[4]; const float* b1 = (const float*)d_in[5];
  const float* w2  = (const float*)d_in[6]; const float* b2 = (const float*)d_in[7];
  const float* w3  = (const float*)d_in[8]; const float* b3 = (const float*)d_in[9];

  const size_t NM = (size_t)NB*NCH*NPOS;          // 16,777,216 elems per matrix
  unsigned short* Qb = (unsigned short*)d_ws;     // bf16, 33.55 MB each
  unsigned short* Kb = Qb + NM;
  unsigned short* Vb = Kb + NM;
  unsigned short* Pb = Vb + NM;
  float* out = (float*)d_out;

  (void)hipFuncSetAttribute((const void*)rc_attention_mfma,
                            hipFuncAttributeMaxDynamicSharedMemorySize, 131072);

  rc_conv_in<<<dim3(128, NB, 2), 256, 0, stream>>>(x, att, w0,b0, w1,b1, w2,b2,
                                                   Qb, Kb, Vb);

  rc_attention_mfma<<<dim3(NB*NCH/2), 512, 131072, stream>>>(Qb, Kb, Vb, Pb);

  rc_conv_out<<<dim3(128, NB), 256, 0, stream>>>(Pb, w3, b3, out);
}